// Round 8
// baseline (2585.973 us; speedup 1.0000x reference)
//
#include <hip/hip_runtime.h>

#define Fdim 128
#define Bsz  8192
#define Pn   6
#define EPSI 1e-5f
#define X2P 136       // x2 tile pitch (halves)
#define X1P 72        // x1 half-tile pitch (halves)

typedef _Float16 half8  __attribute__((ext_vector_type(8)));
typedef _Float16 half4t __attribute__((ext_vector_type(4)));
typedef float    float4t  __attribute__((ext_vector_type(4)));
typedef float    float16t __attribute__((ext_vector_type(16)));

__constant__ int PAIR_A[6] = {0,0,0,1,1,2};
__constant__ int PAIR_B[6] = {1,2,3,2,3,3};

// ---------------------------------------------------------------------------
// Kernel 1: W [128 x 16384] fp32 -> f16 B-frags for mfma_f32_32x32x16_f16.
// R6-proven layout: half8 slot = c16*256 + nt*64 + q2*32 + ol32 holds
// B[k = c16*16 + q2*8 + jj][n = nt*32 + ol32], jj = 0..7.
// Thread map chosen for COALESCED READS: o = t>>11, koct = t&2047 ->
// each lane reads 32 contiguous bytes, wave reads 2 KB contiguous.
// Block 1023 also zero-inits ssum/ssq.
// ---------------------------------------------------------------------------
__global__ __launch_bounds__(256) void wprep(const float* __restrict__ W,
                                             _Float16* __restrict__ Wws,
                                             float* __restrict__ szero) {
    int t    = blockIdx.x * 256 + threadIdx.x;  // 0..262143
    int o    = t >> 11;        // 0..127
    int koct = t & 2047;       // k-octet
    const float4t* src = (const float4t*)(W + (size_t)o * 16384 + koct * 8);
    float4t a0 = src[0];
    float4t a1 = src[1];
    half8 h;
    h[0] = (_Float16)a0[0]; h[1] = (_Float16)a0[1];
    h[2] = (_Float16)a0[2]; h[3] = (_Float16)a0[3];
    h[4] = (_Float16)a1[0]; h[5] = (_Float16)a1[1];
    h[6] = (_Float16)a1[2]; h[7] = (_Float16)a1[3];
    int c16 = koct >> 1;
    int q2  = koct & 1;
    int nt  = o >> 5;
    int ol  = o & 31;
    *(half8*)(Wws + ((size_t)c16 * 256 + nt * 64 + q2 * 32 + ol) * 8) = h;
    if (blockIdx.x == 1023) {
        for (int z = 0; z < 6; ++z) szero[threadIdx.x + 256 * z] = 0.f;
    }
}

// ---------------------------------------------------------------------------
// Kernel 2: per (pair, 128-row m-block, 64-col n-half), 32x32x16 MFMA.
// R6 structure (proven no-spill) + ring-8 W prefetch with cross-jc targets:
// consumption c16 = kh*512 + il*8 + jc; step il prefetches il+8 (same jc) or
// the NEXT jc's head (il>=56) so the stream never restarts cold. kh heads
// are warmed explicitly (jc=7 tails write harmless garbage, overwritten).
// ---------------------------------------------------------------------------
__global__ __launch_bounds__(256, 3) void gemm(const float* __restrict__ x,
                                               const _Float16* __restrict__ Wws,
                                               _Float16* __restrict__ yws,
                                               float* __restrict__ ssum,
                                               float* __restrict__ ssq) {
    __shared__ _Float16 x2t[128 * X2P];    // 34816 B
    __shared__ _Float16 x1th[128 * X1P];   // 18432 B

    int bid  = blockIdx.x;
    int p    = bid >> 7;
    int rem  = bid & 127;
    int mblk = rem >> 1;
    int nh   = rem & 1;
    int m0   = mblk * 128;
    int v1   = PAIR_A[p];
    int v2   = PAIR_B[p];
    int tid  = threadIdx.x;

    int lane  = tid & 63;
    int w     = tid >> 6;
    int ol32  = lane & 31;
    int q2    = lane >> 5;
    int rbase = w * 32;
    int ntg0  = nh * 2;

    const half8* wb  = (const half8*)Wws;
    const half8* wp0 = wb + (size_t)ntg0 * 64 + lane;   // + c16*256 per step
    const half8* wp1 = wp0 + 64;
    const float* x1src = x + ((size_t)v1 * Bsz + m0) * Fdim;

    // ---- stage x2 tile (full 128x128, fp32 -> f16) ------------------------
    {
        const float4t* s2p = (const float4t*)(x + ((size_t)v2 * Bsz + m0) * Fdim);
        for (int it = 0; it < 16; ++it) {
            int idx = it * 256 + tid;
            int row = idx >> 5;
            int col = (idx & 31) * 4;
            float4t b = s2p[idx];
            half4t h2; h2[0]=(_Float16)b[0]; h2[1]=(_Float16)b[1];
                       h2[2]=(_Float16)b[2]; h2[3]=(_Float16)b[3];
            *(half4t*)&x2t[row * X2P + col] = h2;
        }
    }
    // ---- stage x1 half 0 --------------------------------------------------
    for (int it = 0; it < 8; ++it) {
        int idx = it * 256 + tid;
        int row = idx >> 4;
        int c4  = (idx & 15) * 4;
        float4t a = *(const float4t*)(x1src + (size_t)row * Fdim + c4);
        half4t h1; h1[0]=(_Float16)a[0]; h1[1]=(_Float16)a[1];
                   h1[2]=(_Float16)a[2]; h1[3]=(_Float16)a[3];
        *(half4t*)&x1th[row * X1P + c4] = h1;
    }

    float16t acc0, acc1;
#pragma unroll
    for (int z = 0; z < 16; ++z) { acc0[z] = 0.f; acc1[z] = 0.f; }

    half8 rb0[8], rb1[8];
    // warm ring for kh=0, jc=0 heads: c16 = z*8 (issued before barrier drain)
#pragma unroll
    for (int z = 0; z < 8; ++z) {
        rb0[z] = wp0[(size_t)(z * 8) * 256];
        rb1[z] = wp1[(size_t)(z * 8) * 256];
    }
    __syncthreads();

    for (int kh = 0; kh < 2; ++kh) {
        const half8* wk0 = wp0 + (size_t)kh * 131072;   // c16 base of this half
        const half8* wk1 = wp1 + (size_t)kh * 131072;

        for (int jc = 0; jc < 8; ++jc) {
            half8 x2f = *(const half8*)&x2t[(rbase + ol32) * X2P + jc * 16 + q2 * 8];
#pragma unroll
            for (int i8 = 0; i8 < 8; ++i8) {
                half8 x1f = *(const half8*)&x1th[(rbase + ol32) * X1P + i8 * 8];
#pragma unroll
                for (int ii = 0; ii < 8; ++ii) {
                    const int il = i8 * 8 + ii;
                    // prefetch target: 8 steps ahead in consumption order
                    // il<56 -> (il+8, jc); il>=56 -> (il-56, jc+1). For jc=7
                    // the latter reads harmless in-range data; those slots are
                    // re-warmed at the kh boundary before consumption.
                    size_t pfo = (il < 56)
                        ? ((size_t)((il + 8) * 8 + jc) * 256)
                        : ((size_t)((il - 56) * 8 + jc + 1) * 256);
                    half8 n0 = wk0[pfo];
                    half8 n1 = wk1[pfo];
                    half8 a  = x2f * x1f[ii];      // 4 pk_mul shared by 2 MFMAs
                    acc0 = __builtin_amdgcn_mfma_f32_32x32x16_f16(a, rb0[il & 7], acc0, 0, 0, 0);
                    acc1 = __builtin_amdgcn_mfma_f32_32x32x16_f16(a, rb1[il & 7], acc1, 0, 0, 0);
                    rb0[il & 7] = n0;
                    rb1[il & 7] = n1;
                }
            }
        }

        if (kh == 0) {
            __syncthreads();
            // restage x1 half 1
            for (int it = 0; it < 8; ++it) {
                int idx = it * 256 + tid;
                int row = idx >> 4;
                int c4  = (idx & 15) * 4;
                float4t a = *(const float4t*)(x1src + (size_t)row * Fdim + 64 + c4);
                half4t h1; h1[0]=(_Float16)a[0]; h1[1]=(_Float16)a[1];
                           h1[2]=(_Float16)a[2]; h1[3]=(_Float16)a[3];
                *(half4t*)&x1th[row * X1P + c4] = h1;
            }
            // warm ring for kh=1, jc=0 heads: c16 = 512 + z*8
#pragma unroll
            for (int z = 0; z < 8; ++z) {
                rb0[z] = wp0[(size_t)(131072 + z * 8 * 256)];
                rb1[z] = wp1[(size_t)(131072 + z * 8 * 256)];
            }
            __syncthreads();
        }
    }

    // ---- epilogue: store y (f16) + per-o stats ----------------------------
    // C/D layout: col = lane&31, row_local = (reg&3) + 4*(lane>>5) + 8*(reg>>2)
    float sum0 = 0.f, sq0 = 0.f, sum1 = 0.f, sq1 = 0.f;
    int col0 = ntg0 * 32 + ol32;
    int col1 = col0 + 32;
#pragma unroll
    for (int reg = 0; reg < 16; ++reg) {
        int rl = (reg & 3) + 4 * q2 + 8 * (reg >> 2);
        size_t row = (size_t)p * Bsz + m0 + rbase + rl;
        float v0 = acc0[reg];
        sum0 += v0; sq0 += v0 * v0;
        yws[row * Fdim + col0] = (_Float16)v0;
        float v1e = acc1[reg];
        sum1 += v1e; sq1 += v1e * v1e;
        yws[row * Fdim + col1] = (_Float16)v1e;
    }
    sum0 += __shfl_xor(sum0, 32, 64);  sq0 += __shfl_xor(sq0, 32, 64);
    sum1 += __shfl_xor(sum1, 32, 64);  sq1 += __shfl_xor(sq1, 32, 64);
    if (q2 == 0) {
        atomicAdd(&ssum[p * Fdim + col0], sum0);
        atomicAdd(&ssq [p * Fdim + col0], sq0);
        atomicAdd(&ssum[p * Fdim + col1], sum1);
        atomicAdd(&ssq [p * Fdim + col1], sq1);
    }
}

// ---------------------------------------------------------------------------
// Kernel 3: BN (train-mode batch stats, biased var) + ReLU, f16 y -> fp32 out.
// ---------------------------------------------------------------------------
__global__ __launch_bounds__(256) void bnrelu(const _Float16* __restrict__ yws,
                                              const float* __restrict__ ssum,
                                              const float* __restrict__ ssq,
                                              const float* __restrict__ gamma,
                                              const float* __restrict__ beta,
                                              float* __restrict__ out) {
    __shared__ float gs[128], sh[128];
    size_t ebase = (size_t)blockIdx.x * 1024;
    int p = (int)(ebase >> 20);            // B*F = 2^20
    int t = threadIdx.x;
    if (t < 128) {
        float mean = ssum[p * Fdim + t] * (1.0f / 8192.0f);
        float var  = ssq [p * Fdim + t] * (1.0f / 8192.0f) - mean * mean;
        float g    = gamma[t] * rsqrtf(var + EPSI);
        gs[t] = g;
        sh[t] = beta[t] - g * mean;
    }
    __syncthreads();
    size_t e0 = ebase + (size_t)t * 4;
    int o0 = (int)(e0 & 127);
    half4t y = *(const half4t*)(yws + e0);
    float4t r;
#pragma unroll
    for (int l = 0; l < 4; ++l) {
        float v = fmaf(gs[o0 + l], (float)y[l], sh[o0 + l]);
        r[l] = v > 0.f ? v : 0.f;
    }
    *(float4t*)(out + e0) = r;
}

// ---------------------------------------------------------------------------
extern "C" void kernel_launch(void* const* d_in, const int* in_sizes, int n_in,
                              void* d_out, int out_size, void* d_ws, size_t ws_size,
                              hipStream_t stream) {
    const float* x     = (const float*)d_in[0];
    const float* W     = (const float*)d_in[1];
    // d_in[2] = linear bias b: cancelled by train-mode BN.
    const float* gamma = (const float*)d_in[3];
    const float* beta  = (const float*)d_in[4];
    float* out = (float*)d_out;

    char* ws = (char*)d_ws;
    _Float16* yws = (_Float16*)ws;                       // 12,582,912 B
    _Float16* Wws = (_Float16*)(ws + 12582912);          //  4,194,304 B (+pad)
    float*    ssum = (float*)(ws + 12582912 + 4194304 + 65536);
    float*    ssq  = ssum + Pn * Fdim;

    wprep<<<1024, 256, 0, stream>>>(W, Wws, ssum);       // also zeroes ssum+ssq
    gemm<<<768, 256, 0, stream>>>(x, Wws, yws, ssum, ssq);
    bnrelu<<<6144, 256, 0, stream>>>(yws, ssum, ssq, gamma, beta, out);
}

// Round 9
// 335.898 us; speedup vs baseline: 7.6987x; 7.6987x over previous
//
#include <hip/hip_runtime.h>

#define Fdim 128
#define Bsz  8192
#define Pn   6
#define EPSI 1e-5f
#define X2P 136       // x2 tile pitch (halves)
#define X1P 72        // x1 half-tile pitch (halves)

typedef _Float16 half8  __attribute__((ext_vector_type(8)));
typedef _Float16 half4t __attribute__((ext_vector_type(4)));
typedef float    float4t  __attribute__((ext_vector_type(4)));
typedef float    float16t __attribute__((ext_vector_type(16)));

__constant__ int PAIR_A[6] = {0,0,0,1,1,2};
__constant__ int PAIR_B[6] = {1,2,3,2,3,3};

// ---------------------------------------------------------------------------
// Kernel 1: W [128 x 16384] fp32 -> f16 B-frags for mfma_f32_32x32x16_f16.
// Layout (R6-proven): half8 slot = c16*256 + nt*64 + q2*32 + ol32 holds
// B[k = c16*16 + q2*8 + jj][n = nt*32 + ol32], jj = 0..7.  Coalesced reads.
// Block 1023 zero-inits ssum/ssq.
// ---------------------------------------------------------------------------
__global__ __launch_bounds__(256) void wprep(const float* __restrict__ W,
                                             _Float16* __restrict__ Wws,
                                             float* __restrict__ szero) {
    int t    = blockIdx.x * 256 + threadIdx.x;  // 0..262143
    int o    = t >> 11;        // 0..127
    int koct = t & 2047;       // k-octet
    const float4t* src = (const float4t*)(W + (size_t)o * 16384 + koct * 8);
    float4t a0 = src[0];
    float4t a1 = src[1];
    half8 h;
    h[0] = (_Float16)a0[0]; h[1] = (_Float16)a0[1];
    h[2] = (_Float16)a0[2]; h[3] = (_Float16)a0[3];
    h[4] = (_Float16)a1[0]; h[5] = (_Float16)a1[1];
    h[6] = (_Float16)a1[2]; h[7] = (_Float16)a1[3];
    int c16 = koct >> 1;
    int q2  = koct & 1;
    int nt  = o >> 5;
    int ol  = o & 31;
    *(half8*)(Wws + ((size_t)c16 * 256 + nt * 64 + q2 * 32 + ol) * 8) = h;
    if (blockIdx.x == 1023) {
        for (int z = 0; z < 6; ++z) szero[threadIdx.x + 256 * z] = 0.f;
    }
}

// ---------------------------------------------------------------------------
// Kernel 2: split-K GEMM. Block = (pair, 128-row m-block, K-half kh): computes
// the FULL 128-col output for i in [kh*64, kh*64+64), j in [0,128). Waves 2x2:
// wave = 2 m-tiles x 2 n-tiles of 32 (M=2,N=2) -> per kFLOP: 0.06 pk_mul AND
// 16 B of W (best corner of the measured R4/R5/R6 frontier). Distance-2 W
// prefetch (R5-proven, ring-8 spills per R7/R8). No mid-kernel barriers.
// Partial y (f16) -> y0/y1; stats done in bnstats.
// ---------------------------------------------------------------------------
__global__ __launch_bounds__(256, 3) void gemm(const float* __restrict__ x,
                                               const _Float16* __restrict__ Wws,
                                               _Float16* __restrict__ y0,
                                               _Float16* __restrict__ y1) {
    __shared__ _Float16 x2t[128 * X2P];    // 34816 B: full 128 rows x 128 j
    __shared__ _Float16 x1th[128 * X1P];   // 18432 B: 128 rows x this block's 64 i

    int bid  = blockIdx.x;
    int p    = bid >> 7;
    int rem  = bid & 127;
    int mblk = rem >> 1;          // 64 m-blocks of 128 rows
    int kh   = rem & 1;           // K-half: i in [kh*64, kh*64+64)
    int m0   = mblk * 128;
    int v1   = PAIR_A[p];
    int v2   = PAIR_B[p];
    int tid  = threadIdx.x;

    // ---- stage x2 tile (full 128x128, fp32 -> f16) ------------------------
    {
        const float4t* s2p = (const float4t*)(x + ((size_t)v2 * Bsz + m0) * Fdim);
        for (int it = 0; it < 16; ++it) {
            int idx = it * 256 + tid;
            int row = idx >> 5;
            int col = (idx & 31) * 4;
            float4t b = s2p[idx];
            half4t h2; h2[0]=(_Float16)b[0]; h2[1]=(_Float16)b[1];
                       h2[2]=(_Float16)b[2]; h2[3]=(_Float16)b[3];
            *(half4t*)&x2t[row * X2P + col] = h2;
        }
    }
    // ---- stage x1 half-tile: 128 rows x 64 i-cols (this block's half) -----
    {
        const float* x1src = x + ((size_t)v1 * Bsz + m0) * Fdim + kh * 64;
        for (int it = 0; it < 8; ++it) {
            int idx = it * 256 + tid;
            int row = idx >> 4;
            int c4  = (idx & 15) * 4;
            float4t a = *(const float4t*)(x1src + (size_t)row * Fdim + c4);
            half4t h1; h1[0]=(_Float16)a[0]; h1[1]=(_Float16)a[1];
                       h1[2]=(_Float16)a[2]; h1[3]=(_Float16)a[3];
            *(half4t*)&x1th[row * X1P + c4] = h1;
        }
    }
    __syncthreads();

    int lane  = tid & 63;
    int w     = tid >> 6;
    int wm    = w >> 1;           // wave m-half: rows wm*64 + {0,32} + ...
    int wn    = w & 1;            // wave n-half: cols wn*64 + {0,32}
    int ol32  = lane & 31;
    int q2    = lane >> 5;
    int rb0r  = wm * 64;          // first m-tile row base
    int rb1r  = rb0r + 32;        // second m-tile
    int ntg0  = wn * 2;
    // W stream base for this (kh, ntg): slot((il,jc)) = +(il*8+jc)*256
    const half8* wp0 = (const half8*)Wws + (size_t)kh * 131072 + ntg0 * 64 + lane;
    const half8* wp1 = wp0 + 64;

    float16t a00, a01, a10, a11;
#pragma unroll
    for (int z = 0; z < 16; ++z) { a00[z]=0.f; a01[z]=0.f; a10[z]=0.f; a11[z]=0.f; }

    for (int jc = 0; jc < 8; ++jc) {
        // x2 fragments (one per m-tile): constant across the 64-i sweep
        half8 x2f0 = *(const half8*)&x2t[(rb0r + ol32) * X2P + jc * 16 + q2 * 8];
        half8 x2f1 = *(const half8*)&x2t[(rb1r + ol32) * X2P + jc * 16 + q2 * 8];

        // distance-2 prefetch pipeline (R5-proven shape)
        half8 bfa0 = wp0[(size_t)(0 * 8 + jc) * 256];
        half8 bfa1 = wp1[(size_t)(0 * 8 + jc) * 256];
        half8 bfb0 = wp0[(size_t)(1 * 8 + jc) * 256];
        half8 bfb1 = wp1[(size_t)(1 * 8 + jc) * 256];

        for (int i8 = 0; i8 < 8; ++i8) {
            half8 x1f0 = *(const half8*)&x1th[(rb0r + ol32) * X1P + i8 * 8];
            half8 x1f1 = *(const half8*)&x1th[(rb1r + ol32) * X1P + i8 * 8];
#pragma unroll
            for (int ii = 0; ii < 8; ++ii) {
                int il  = i8 * 8 + ii;
                int ipl = (il < 62) ? (il + 2) : 63;
                half8 bn0 = wp0[(size_t)(ipl * 8 + jc) * 256];
                half8 bn1 = wp1[(size_t)(ipl * 8 + jc) * 256];
                half8 af0 = x2f0 * x1f0[ii];   // 4 pk_mul
                half8 af1 = x2f1 * x1f1[ii];   // 4 pk_mul  -> 8 pk per 4 MFMAs
                a00 = __builtin_amdgcn_mfma_f32_32x32x16_f16(af0, bfa0, a00, 0, 0, 0);
                a01 = __builtin_amdgcn_mfma_f32_32x32x16_f16(af0, bfa1, a01, 0, 0, 0);
                a10 = __builtin_amdgcn_mfma_f32_32x32x16_f16(af1, bfa0, a10, 0, 0, 0);
                a11 = __builtin_amdgcn_mfma_f32_32x32x16_f16(af1, bfa1, a11, 0, 0, 0);
                bfa0 = bfb0; bfa1 = bfb1;
                bfb0 = bn0;  bfb1 = bn1;
            }
        }
    }

    // ---- epilogue: store partial y (f16) ----------------------------------
    _Float16* yp = kh ? y1 : y0;
    int col0 = wn * 64 + ol32;
#pragma unroll
    for (int reg = 0; reg < 16; ++reg) {
        int rl = (reg & 3) + 4 * q2 + 8 * (reg >> 2);
        size_t row0 = (size_t)p * Bsz + m0 + rb0r + rl;
        size_t row1 = row0 + 32;
        yp[row0 * Fdim + col0]      = (_Float16)a00[reg];
        yp[row0 * Fdim + col0 + 32] = (_Float16)a01[reg];
        yp[row1 * Fdim + col0]      = (_Float16)a10[reg];
        yp[row1 * Fdim + col0 + 32] = (_Float16)a11[reg];
    }
}

// ---------------------------------------------------------------------------
// Kernel 2b: merge K-halves (y = y0+y1, written f16 in-place into y0) and
// accumulate per-(pair,o) sum/sumsq via LDS then global atomics.
// Block = 64 consecutive rows of one pair.
// ---------------------------------------------------------------------------
__global__ __launch_bounds__(256) void bnstats(_Float16* __restrict__ y0,
                                               const _Float16* __restrict__ y1,
                                               float* __restrict__ ssum,
                                               float* __restrict__ ssq) {
    __shared__ float sS[128], sQ[128];
    int t = threadIdx.x;
    if (t < 128) { sS[t] = 0.f; sQ[t] = 0.f; }
    __syncthreads();
    int col8 = (t & 15) * 8;
    int rw   = t >> 4;              // 0..15
    size_t grow0 = (size_t)blockIdx.x * 64;
    float fs[8], fq[8];
#pragma unroll
    for (int z = 0; z < 8; ++z) { fs[z] = 0.f; fq[z] = 0.f; }
    for (int k = 0; k < 4; ++k) {
        size_t idx = (grow0 + rw + 16 * k) * Fdim + col8;
        half8 a = *(const half8*)(y0 + idx);
        half8 b = *(const half8*)(y1 + idx);
        half8 s;
#pragma unroll
        for (int z = 0; z < 8; ++z) {
            float v = (float)a[z] + (float)b[z];
            fs[z] += v; fq[z] += v * v;
            s[z] = (_Float16)v;
        }
        *(half8*)(y0 + idx) = s;
    }
#pragma unroll
    for (int z = 0; z < 8; ++z) {
        atomicAdd(&sS[col8 + z], fs[z]);
        atomicAdd(&sQ[col8 + z], fq[z]);
    }
    __syncthreads();
    int p = (int)(grow0 >> 13);     // 8192 rows per pair
    if (t < 128) {
        atomicAdd(&ssum[p * Fdim + t], sS[t]);
        atomicAdd(&ssq [p * Fdim + t], sQ[t]);
    }
}

// ---------------------------------------------------------------------------
// Kernel 3: BN (train-mode batch stats, biased var) + ReLU, f16 y -> fp32 out.
// ---------------------------------------------------------------------------
__global__ __launch_bounds__(256) void bnrelu(const _Float16* __restrict__ yws,
                                              const float* __restrict__ ssum,
                                              const float* __restrict__ ssq,
                                              const float* __restrict__ gamma,
                                              const float* __restrict__ beta,
                                              float* __restrict__ out) {
    __shared__ float gs[128], sh[128];
    size_t ebase = (size_t)blockIdx.x * 1024;
    int p = (int)(ebase >> 20);            // B*F = 2^20
    int t = threadIdx.x;
    if (t < 128) {
        float mean = ssum[p * Fdim + t] * (1.0f / 8192.0f);
        float var  = ssq [p * Fdim + t] * (1.0f / 8192.0f) - mean * mean;
        float g    = gamma[t] * rsqrtf(var + EPSI);
        gs[t] = g;
        sh[t] = beta[t] - g * mean;
    }
    __syncthreads();
    size_t e0 = ebase + (size_t)t * 4;
    int o0 = (int)(e0 & 127);
    half4t y = *(const half4t*)(yws + e0);
    float4t r;
#pragma unroll
    for (int l = 0; l < 4; ++l) {
        float v = fmaf(gs[o0 + l], (float)y[l], sh[o0 + l]);
        r[l] = v > 0.f ? v : 0.f;
    }
    *(float4t*)(out + e0) = r;
}

// ---------------------------------------------------------------------------
extern "C" void kernel_launch(void* const* d_in, const int* in_sizes, int n_in,
                              void* d_out, int out_size, void* d_ws, size_t ws_size,
                              hipStream_t stream) {
    const float* x     = (const float*)d_in[0];
    const float* W     = (const float*)d_in[1];
    // d_in[2] = linear bias b: cancelled by train-mode BN.
    const float* gamma = (const float*)d_in[3];
    const float* beta  = (const float*)d_in[4];
    float* out = (float*)d_out;

    char* ws = (char*)d_ws;
    _Float16* y0  = (_Float16*)ws;                       // 12,582,912 B
    _Float16* y1  = (_Float16*)(ws + 12582912);          // 12,582,912 B
    _Float16* Wws = (_Float16*)(ws + 25165824);          //  4,194,304 B
    float*    ssum = (float*)(ws + 25165824 + 4194304);
    float*    ssq  = ssum + Pn * Fdim;

    wprep<<<1024, 256, 0, stream>>>(W, Wws, ssum);       // also zeroes ssum+ssq
    gemm<<<768, 256, 0, stream>>>(x, Wws, y0, y1);
    bnstats<<<768, 256, 0, stream>>>(y0, y1, ssum, ssq);
    bnrelu<<<6144, 256, 0, stream>>>(y0, ssum, ssq, gamma, beta, out);
}

// Round 10
// 290.508 us; speedup vs baseline: 8.9016x; 1.1562x over previous
//
#include <hip/hip_runtime.h>

#define Fdim 128
#define Bsz  8192
#define Pn   6
#define EPSI 1e-5f
#define X1P 68        // x1 tile pitch (halves): 8B-aligned b64 reads, 2-way banks (free)

typedef _Float16 half8  __attribute__((ext_vector_type(8)));
typedef _Float16 half4t __attribute__((ext_vector_type(4)));
typedef float    float4t  __attribute__((ext_vector_type(4)));
typedef float    float16t __attribute__((ext_vector_type(16)));

typedef unsigned int u32;
typedef const __attribute__((address_space(1))) u32* gp_t;
typedef __attribute__((address_space(3))) u32* lp_t;

__constant__ int PAIR_A[6] = {0,0,0,1,1,2};
__constant__ int PAIR_B[6] = {1,2,3,2,3,3};

// ---------------------------------------------------------------------------
// Kernel 1: W [128 x 16384] fp32 -> f16 B-frags (mfma_f32_32x32x16_f16) in
// EXACT chunk-linear consumption order:
//   half8 slot t: lane=t&63 (ol32=lane&31,q2=lane>>5), nt=(t>>6)&3,
//   di=(t>>8)&3, cg=t>>10 (global chunk 0..255: cg = kh*128 + jc*16 + ig)
//   i = kh*64 + ig*4 + di ;  value = W[n = nt*32+ol32][k = i*128 + jc*16 +
//   q2*8 + jj], jj=0..7.  One chunk = 16 KB contiguous = (4 di x 4 nt x 64).
// Writes fully coalesced; block 1023 zero-inits ssum/ssq.
// ---------------------------------------------------------------------------
__global__ __launch_bounds__(256) void wprep(const float* __restrict__ W,
                                             _Float16* __restrict__ Wws,
                                             float* __restrict__ szero) {
    int t    = blockIdx.x * 256 + threadIdx.x;  // 0..262143
    int lane = t & 63;
    int nt   = (t >> 6) & 3;
    int di   = (t >> 8) & 3;
    int cg   = t >> 10;
    int ig   = cg & 15;
    int jc   = (cg >> 4) & 7;
    int kh   = cg >> 7;
    int q2   = lane >> 5;
    int o    = nt * 32 + (lane & 31);
    int i    = kh * 64 + ig * 4 + di;
    const float4t* src = (const float4t*)(W + (size_t)o * 16384 + i * 128 + jc * 16 + q2 * 8);
    float4t a0 = src[0];
    float4t a1 = src[1];
    half8 h;
    h[0] = (_Float16)a0[0]; h[1] = (_Float16)a0[1];
    h[2] = (_Float16)a0[2]; h[3] = (_Float16)a0[3];
    h[4] = (_Float16)a1[0]; h[5] = (_Float16)a1[1];
    h[6] = (_Float16)a1[2]; h[7] = (_Float16)a1[3];
    *(half8*)(Wws + (size_t)t * 8) = h;
    if (blockIdx.x == 1023) {
        for (int z = 0; z < 6; ++z) szero[threadIdx.x + 256 * z] = 0.f;
    }
}

// ---------------------------------------------------------------------------
// Kernel 2: block = (pair, 128-row m-block, K-half kh): full 128-n output for
// i in [kh*64,kh*64+64). 128 K-chunks of 64 k (one j-window of 16 x 4 i).
// W staged via async global_load_lds into a 2x16KB LDS double buffer (one
// barrier per chunk; prefetch issued a full chunk ahead -> barrier vmcnt
// drain is cheap). Waves 2m x 2n tiles; A-frags on the fly from LDS x1 +
// register x2f (reloaded from global once per 16 chunks). Zero sync W loads.
// ---------------------------------------------------------------------------
__global__ __launch_bounds__(256, 3) void gemm(const float* __restrict__ x,
                                               const _Float16* __restrict__ Wws,
                                               _Float16* __restrict__ y0,
                                               _Float16* __restrict__ y1) {
    __shared__ _Float16 x1th[128 * X1P];                    // 17408 B
    __shared__ __align__(16) _Float16 wbufs[2][8192];       // 2 x 16384 B

    int bid  = blockIdx.x;
    int p    = bid >> 7;
    int rem  = bid & 127;
    int mblk = rem >> 1;
    int kh   = rem & 1;
    int m0   = mblk * 128;
    int v1   = PAIR_A[p];
    int v2   = PAIR_B[p];
    int tid  = threadIdx.x;
    int lane = tid & 63;
    int w    = tid >> 6;
    int ol32 = lane & 31;
    int q2   = lane >> 5;
    int wm   = w >> 1;
    int wn   = w & 1;
    int rb0r = wm * 64;
    int rb1r = rb0r + 32;
    int ntg0 = wn * 2;
    int ntg1 = ntg0 + 1;

    const char* wsrc = (const char*)Wws + (size_t)(kh * 128) * 16384;
    const float* x2base = x + ((size_t)v2 * Bsz + m0) * Fdim;

    // ---- stage x1 tile: 128 rows x this half's 64 i (fp32 -> f16) ---------
    {
        const float* x1src = x + ((size_t)v1 * Bsz + m0) * Fdim + kh * 64;
        for (int it = 0; it < 8; ++it) {
            int idx = it * 256 + tid;
            int row = idx >> 4;
            int c4  = (idx & 15) * 4;
            float4t a = *(const float4t*)(x1src + (size_t)row * Fdim + c4);
            half4t h1; h1[0]=(_Float16)a[0]; h1[1]=(_Float16)a[1];
                       h1[2]=(_Float16)a[2]; h1[3]=(_Float16)a[3];
            *(half4t*)&x1th[row * X1P + c4] = h1;
        }
    }
    // ---- async prefetch of chunk 0 into wbufs[0] --------------------------
    {
        const char* g = wsrc + w * 1024 + lane * 16;
        char* l = (char*)&wbufs[0][0] + w * 1024 + lane * 16;
#pragma unroll
        for (int r = 0; r < 4; ++r)
            __builtin_amdgcn_global_load_lds((gp_t)(const void*)(g + r * 4096),
                                             (lp_t)(void*)(l + r * 4096), 16, 0, 0);
    }
    __syncthreads();   // drains x1 ds_writes + chunk-0 glds

    float16t a00, a01, a10, a11;
#pragma unroll
    for (int z = 0; z < 16; ++z) { a00[z]=0.f; a01[z]=0.f; a10[z]=0.f; a11[z]=0.f; }

    half8 x2f0, x2f1;
    for (int c = 0; c < 128; ++c) {
        // prefetch chunk c+1 (c=127 over-reads 16 KB into the ws pad)
        {
            const char* g = wsrc + (size_t)(c + 1) * 16384 + w * 1024 + lane * 16;
            char* l = (char*)&wbufs[(c + 1) & 1][0] + w * 1024 + lane * 16;
#pragma unroll
            for (int r = 0; r < 4; ++r)
                __builtin_amdgcn_global_load_lds((gp_t)(const void*)(g + r * 4096),
                                                 (lp_t)(void*)(l + r * 4096), 16, 0, 0);
        }
        int jc = c >> 4;
        int ig = c & 15;
        if (ig == 0) {      // j-window changed: reload x2 fragments (global)
            const float* xb0 = x2base + (size_t)(rb0r + ol32) * Fdim + jc * 16 + q2 * 8;
            const float* xb1 = x2base + (size_t)(rb1r + ol32) * Fdim + jc * 16 + q2 * 8;
            float4t b0 = *(const float4t*)xb0, b1 = *(const float4t*)(xb0 + 4);
            float4t c0 = *(const float4t*)xb1, c1 = *(const float4t*)(xb1 + 4);
#pragma unroll
            for (int z = 0; z < 4; ++z) {
                x2f0[z] = (_Float16)b0[z]; x2f0[z + 4] = (_Float16)b1[z];
                x2f1[z] = (_Float16)c0[z]; x2f1[z + 4] = (_Float16)c1[z];
            }
        }
        // x1 quads for this chunk's 4 i values
        half4t x1q0 = *(const half4t*)&x1th[(rb0r + ol32) * X1P + ig * 4];
        half4t x1q1 = *(const half4t*)&x1th[(rb1r + ol32) * X1P + ig * 4];

        const _Float16* wbuf = &wbufs[c & 1][0];
#pragma unroll
        for (int di = 0; di < 4; ++di) {
            half8 w0 = *(const half8*)&wbuf[((di * 4 + ntg0) * 64 + lane) * 8];
            half8 w1 = *(const half8*)&wbuf[((di * 4 + ntg1) * 64 + lane) * 8];
            half8 af0 = x2f0 * x1q0[di];   // 4 pk_mul
            half8 af1 = x2f1 * x1q1[di];   // 4 pk_mul
            a00 = __builtin_amdgcn_mfma_f32_32x32x16_f16(af0, w0, a00, 0, 0, 0);
            a01 = __builtin_amdgcn_mfma_f32_32x32x16_f16(af0, w1, a01, 0, 0, 0);
            a10 = __builtin_amdgcn_mfma_f32_32x32x16_f16(af1, w0, a10, 0, 0, 0);
            a11 = __builtin_amdgcn_mfma_f32_32x32x16_f16(af1, w1, a11, 0, 0, 0);
        }
        __syncthreads();   // publish chunk c+1 staging; all reads of buf done
    }

    // ---- epilogue: store partial y (f16) ----------------------------------
    // C/D layout: col = lane&31, row_local = (reg&3) + 4*(lane>>5) + 8*(reg>>2)
    _Float16* yp = kh ? y1 : y0;
    int col0 = ntg0 * 32 + ol32;
#pragma unroll
    for (int reg = 0; reg < 16; ++reg) {
        int rl = (reg & 3) + 4 * q2 + 8 * (reg >> 2);
        size_t row0 = (size_t)p * Bsz + m0 + rb0r + rl;
        size_t row1 = row0 + 32;
        yp[row0 * Fdim + col0]      = (_Float16)a00[reg];
        yp[row0 * Fdim + col0 + 32] = (_Float16)a01[reg];
        yp[row1 * Fdim + col0]      = (_Float16)a10[reg];
        yp[row1 * Fdim + col0 + 32] = (_Float16)a11[reg];
    }
}

// ---------------------------------------------------------------------------
// Kernel 2b: merge K-halves (y = y0+y1, f16 in-place into y0) + per-(pair,o)
// sum/sumsq via LDS atomics then global atomics. Block = 64 rows of one pair.
// ---------------------------------------------------------------------------
__global__ __launch_bounds__(256) void bnstats(_Float16* __restrict__ y0,
                                               const _Float16* __restrict__ y1,
                                               float* __restrict__ ssum,
                                               float* __restrict__ ssq) {
    __shared__ float sS[128], sQ[128];
    int t = threadIdx.x;
    if (t < 128) { sS[t] = 0.f; sQ[t] = 0.f; }
    __syncthreads();
    int col8 = (t & 15) * 8;
    int rw   = t >> 4;
    size_t grow0 = (size_t)blockIdx.x * 64;
    float fs[8], fq[8];
#pragma unroll
    for (int z = 0; z < 8; ++z) { fs[z] = 0.f; fq[z] = 0.f; }
    for (int k = 0; k < 4; ++k) {
        size_t idx = (grow0 + rw + 16 * k) * Fdim + col8;
        half8 a = *(const half8*)(y0 + idx);
        half8 b = *(const half8*)(y1 + idx);
        half8 s;
#pragma unroll
        for (int z = 0; z < 8; ++z) {
            float v = (float)a[z] + (float)b[z];
            fs[z] += v; fq[z] += v * v;
            s[z] = (_Float16)v;
        }
        *(half8*)(y0 + idx) = s;
    }
#pragma unroll
    for (int z = 0; z < 8; ++z) {
        atomicAdd(&sS[col8 + z], fs[z]);
        atomicAdd(&sQ[col8 + z], fq[z]);
    }
    __syncthreads();
    int p = (int)(grow0 >> 13);
    if (t < 128) {
        atomicAdd(&ssum[p * Fdim + t], sS[t]);
        atomicAdd(&ssq [p * Fdim + t], sQ[t]);
    }
}

// ---------------------------------------------------------------------------
// Kernel 3: BN (train-mode batch stats, biased var) + ReLU, f16 y -> fp32 out.
// ---------------------------------------------------------------------------
__global__ __launch_bounds__(256) void bnrelu(const _Float16* __restrict__ yws,
                                              const float* __restrict__ ssum,
                                              const float* __restrict__ ssq,
                                              const float* __restrict__ gamma,
                                              const float* __restrict__ beta,
                                              float* __restrict__ out) {
    __shared__ float gs[128], sh[128];
    size_t ebase = (size_t)blockIdx.x * 1024;
    int p = (int)(ebase >> 20);
    int t = threadIdx.x;
    if (t < 128) {
        float mean = ssum[p * Fdim + t] * (1.0f / 8192.0f);
        float var  = ssq [p * Fdim + t] * (1.0f / 8192.0f) - mean * mean;
        float g    = gamma[t] * rsqrtf(var + EPSI);
        gs[t] = g;
        sh[t] = beta[t] - g * mean;
    }
    __syncthreads();
    size_t e0 = ebase + (size_t)t * 4;
    int o0 = (int)(e0 & 127);
    half4t y = *(const half4t*)(yws + e0);
    float4t r;
#pragma unroll
    for (int l = 0; l < 4; ++l) {
        float v = fmaf(gs[o0 + l], (float)y[l], sh[o0 + l]);
        r[l] = v > 0.f ? v : 0.f;
    }
    *(float4t*)(out + e0) = r;
}

// ---------------------------------------------------------------------------
extern "C" void kernel_launch(void* const* d_in, const int* in_sizes, int n_in,
                              void* d_out, int out_size, void* d_ws, size_t ws_size,
                              hipStream_t stream) {
    const float* x     = (const float*)d_in[0];
    const float* W     = (const float*)d_in[1];
    // d_in[2] = linear bias b: cancelled by train-mode BN.
    const float* gamma = (const float*)d_in[3];
    const float* beta  = (const float*)d_in[4];
    float* out = (float*)d_out;

    char* ws = (char*)d_ws;
    _Float16* y0  = (_Float16*)ws;                       // 12,582,912 B
    _Float16* y1  = (_Float16*)(ws + 12582912);          // 12,582,912 B
    _Float16* Wws = (_Float16*)(ws + 25165824);          //  4,194,304 B + 16 KB pad
    float*    ssum = (float*)(ws + 25165824 + 4194304 + 16384);
    float*    ssq  = ssum + Pn * Fdim;

    wprep<<<1024, 256, 0, stream>>>(W, Wws, ssum);       // also zeroes ssum+ssq
    gemm<<<768, 256, 0, stream>>>(x, Wws, y0, y1);
    bnstats<<<768, 256, 0, stream>>>(y0, y1, ssum, ssq);
    bnrelu<<<6144, 256, 0, stream>>>(y0, ssum, ssq, gamma, beta, out);
}